// Round 2
// baseline (1580.118 us; speedup 1.0000x reference)
//
#include <hip/hip_runtime.h>

// POMO decoder: B=64, N=500, E=128, H=8, D=16. All fp32.
// Pipeline:
//   K1 gemm_xw : q  = encF*WqF^T + encL*WqL^T            -> ws_q  [32000,128]
//   K2 gemm_xw : kv = encN*[Wk;Wv]^T                     -> ws_kv [32000,256]
//   K3 attn    : att[b,n,h*16+d] = softmax(qk/4+mask)*v  -> ws_att[32000,128]
//   K4 gemm_xw : mh = att*Wc^T + bc                      -> ws_mh (reuses ws_q)
//   K5 pointer : p = exp(10*tanh(mh*enc^T/sqrt128)+mask) -> d_out (unnormalized), rowsums -> ws_rsum
//   K6 norm    : d_out /= rowsum
// Softmax max-subtraction is skipped: attention logits ~N(0,1.4) (no overflow),
// pointer logits clipped to [-10,10]; exp(-1e9) underflows to exactly 0.

#define B_ 64
#define N_ 500

__device__ __forceinline__ float4 ld4(const float* p) { return *reinterpret_cast<const float4*>(p); }
__device__ __forceinline__ void st4(float* p, const float4 v) { *reinterpret_cast<float4*>(p) = v; }

__device__ __forceinline__ float fast_tanh(float x) {
    const float e = __expf(2.f * x);
    return 1.f - 2.f / (e + 1.f);
}

// C[M,F] = sum_t A_t * W_t^T (+bias). M=32000, K=128 fixed. F in {128,256}.
__global__ __launch_bounds__(256) void gemm_xw(
    const float* __restrict__ A1, const float* __restrict__ W1a, const float* __restrict__ W1b,
    const float* __restrict__ A2, const float* __restrict__ W2a, const float* __restrict__ W2b,
    const float* __restrict__ bias, float* __restrict__ C, const int F, const int nterm)
{
    __shared__ __align__(16) float At[16][68];
    __shared__ __align__(16) float Wt[16][68];
    const int t = threadIdx.x;
    const int rb = blockIdx.y * 64;
    const int fb = blockIdx.x * 64;
    const int r0 = (t >> 4) * 4;
    const int f0 = (t & 15) * 4;
    const int srow = t >> 2;
    const int sde  = (t & 3) * 4;

    float acc[4][4];
#pragma unroll
    for (int i = 0; i < 4; ++i)
#pragma unroll
        for (int j = 0; j < 4; ++j) acc[i][j] = 0.f;

    for (int tt = 0; tt < nterm; ++tt) {
        const float* A  = tt ? A2 : A1;
        const float* Wa = tt ? W2a : W1a;
        const float* Wb = tt ? W2b : W1b;
        const float* W  = (fb < 128) ? Wa : Wb;
        const int fr = (fb & 127) + srow;
        for (int e0 = 0; e0 < 128; e0 += 16) {
            __syncthreads();
            const float4 av = ld4(&A[(size_t)(rb + srow) * 128 + e0 + sde]);
            At[sde + 0][srow] = av.x; At[sde + 1][srow] = av.y;
            At[sde + 2][srow] = av.z; At[sde + 3][srow] = av.w;
            const float4 wv = ld4(&W[(size_t)fr * 128 + e0 + sde]);
            Wt[sde + 0][srow] = wv.x; Wt[sde + 1][srow] = wv.y;
            Wt[sde + 2][srow] = wv.z; Wt[sde + 3][srow] = wv.w;
            __syncthreads();
#pragma unroll
            for (int d = 0; d < 16; ++d) {
                const float4 a4 = ld4(&At[d][r0]);
                const float4 w4 = ld4(&Wt[d][f0]);
                const float a[4] = {a4.x, a4.y, a4.z, a4.w};
                const float w[4] = {w4.x, w4.y, w4.z, w4.w};
#pragma unroll
                for (int i = 0; i < 4; ++i)
#pragma unroll
                    for (int j = 0; j < 4; ++j) acc[i][j] += a[i] * w[j];
            }
        }
    }

    float4 bv = make_float4(0.f, 0.f, 0.f, 0.f);
    if (bias) bv = ld4(&bias[fb + f0]);
#pragma unroll
    for (int i = 0; i < 4; ++i) {
        float4 o;
        o.x = acc[i][0] + bv.x; o.y = acc[i][1] + bv.y;
        o.z = acc[i][2] + bv.z; o.w = acc[i][3] + bv.w;
        st4(&C[(size_t)(rb + r0 + i) * F + fb + f0], o);
    }
}

// Attention, restructured (R2):
//  thread (tr, jq, dg): tr=t>>4 rows 4; jq=(t>>2)&3 j-subset of 16; dg=t&3.
//  QK: thread scores s[4][4] at j0=16*jq+4*dg. exp+mask -> p, partial row sums.
//  PV: thread owns out[4 rows][4 d] (d=4*dg+dd), j over its jq-subset;
//      sibling-lane P fetched via __shfl (same wave: lane bits [1:0] vary).
//  V LDS is transposed+XOR-swizzled: element (d,j) at Vt[d][j ^ 4*(d>>2)]
//      -> PV ds_read_b128 is 2-way (free) instead of 8-way.
//  End: sum reduce over 4 lane-bits (16 shfl), out over jq bits (32 shfl).
//  K/V register-preloaded one chunk ahead to hide HBM latency under compute.
__global__ __launch_bounds__(256, 4) void attn_kernel(
    const float* __restrict__ q, const float* __restrict__ kv,
    const float* __restrict__ mask, float* __restrict__ att)
{
    __shared__ __align__(16) float Qt[16][68];  // [d][row]
    __shared__ __align__(16) float Kt[16][68];  // [d][j]
    __shared__ __align__(16) float Vt[16][68];  // [d][j^swz]
    const int t = threadIdx.x;
    const int lane = t & 63;
    const int rt = blockIdx.x;
    const int h  = blockIdx.y;
    const int b  = blockIdx.z;
    const int tr = t >> 4;        // 0..15 -> rows
    const int jq = (t >> 2) & 3;  // j-subset
    const int dg = t & 3;         // d-group AND score j-slot
    const int r0 = tr * 4;
    const int srow = t >> 2;      // staging row 0..63
    const int sde  = (t & 3) * 4; // staging d-offset
    const int vswz = srow ^ (4 * (t & 3));  // swizzled j for V writes (d>>2 == t&3)

    // stage Q (once)
    {
        const int rg = min(rt * 64 + srow, 499);
        const float4 qa = ld4(&q[((size_t)(b * N_ + rg)) * 128 + h * 16 + sde]);
        Qt[sde + 0][srow] = qa.x; Qt[sde + 1][srow] = qa.y;
        Qt[sde + 2][srow] = qa.z; Qt[sde + 3][srow] = qa.w;
    }

    float out[4][4];
#pragma unroll
    for (int i = 0; i < 4; ++i)
#pragma unroll
        for (int dd = 0; dd < 4; ++dd) out[i][dd] = 0.f;
    float sum[4] = {0.f, 0.f, 0.f, 0.f};

    // shuffle source lanes (lane with same tr,jq but dg=g)
    int src[4];
#pragma unroll
    for (int g = 0; g < 4; ++g) src[g] = (lane & ~3) | g;

    // preload chunk 0
    float4 kreg, vreg;
    {
        const int jg = min(srow, 499);
        const float* kp = &kv[((size_t)(b * N_ + jg)) * 256 + h * 16 + sde];
        kreg = ld4(kp); vreg = ld4(kp + 128);
    }

    for (int jc = 0; jc < 8; ++jc) {
        __syncthreads();  // previous chunk's reads done
        Kt[sde + 0][srow] = kreg.x; Kt[sde + 1][srow] = kreg.y;
        Kt[sde + 2][srow] = kreg.z; Kt[sde + 3][srow] = kreg.w;
        Vt[sde + 0][vswz] = vreg.x; Vt[sde + 1][vswz] = vreg.y;
        Vt[sde + 2][vswz] = vreg.z; Vt[sde + 3][vswz] = vreg.w;
        __syncthreads();  // K/V tile visible
        if (jc < 7) {     // preload next chunk (overlaps with compute below)
            const int jg = min(jc * 64 + 64 + srow, 499);
            const float* kp = &kv[((size_t)(b * N_ + jg)) * 256 + h * 16 + sde];
            kreg = ld4(kp); vreg = ld4(kp + 128);
        }

        // ---- QK: s[4 rows][4 j] at j0 = 16*jq + 4*dg
        const int jloc = jq * 16 + dg * 4;
        float s[4][4];
#pragma unroll
        for (int i = 0; i < 4; ++i)
#pragma unroll
            for (int j = 0; j < 4; ++j) s[i][j] = 0.f;
#pragma unroll
        for (int d = 0; d < 16; ++d) {
            const float4 a4 = ld4(&Qt[d][r0]);
            const float4 k4 = ld4(&Kt[d][jloc]);
            const float a[4] = {a4.x, a4.y, a4.z, a4.w};
            const float k[4] = {k4.x, k4.y, k4.z, k4.w};
#pragma unroll
            for (int i = 0; i < 4; ++i)
#pragma unroll
                for (int j = 0; j < 4; ++j) s[i][j] += a[i] * k[j];
        }

        // ---- exp + mask -> p, partial row sums
        const int jbase = jc * 64 + jloc;
        float p[4][4];
#pragma unroll
        for (int i = 0; i < 4; ++i) {
            const int rgc = min(rt * 64 + r0 + i, 499);
            float4 mv;
            if (jbase < 500) mv = ld4(&mask[((size_t)b * N_ + rgc) * N_ + jbase]);
            else mv = make_float4(-1e9f, -1e9f, -1e9f, -1e9f);
            p[i][0] = __expf(s[i][0] * 0.25f + mv.x);
            p[i][1] = __expf(s[i][1] * 0.25f + mv.y);
            p[i][2] = __expf(s[i][2] * 0.25f + mv.z);
            p[i][3] = __expf(s[i][3] * 0.25f + mv.w);
            sum[i] += p[i][0] + p[i][1] + p[i][2] + p[i][3];
        }

        // ---- PV: out[i][dd] over j in [16*jq, 16*jq+16)
#pragma unroll
        for (int g = 0; g < 4; ++g) {
            const int jb = jq * 16 + 4 * (g ^ dg);  // swizzled read base
            float4 vt[4];
#pragma unroll
            for (int dd = 0; dd < 4; ++dd) vt[dd] = ld4(&Vt[dg * 4 + dd][jb]);
#pragma unroll
            for (int i = 0; i < 4; ++i) {
                const float pg0 = __shfl(p[i][0], src[g], 64);
                const float pg1 = __shfl(p[i][1], src[g], 64);
                const float pg2 = __shfl(p[i][2], src[g], 64);
                const float pg3 = __shfl(p[i][3], src[g], 64);
#pragma unroll
                for (int dd = 0; dd < 4; ++dd)
                    out[i][dd] += pg0 * vt[dd].x + pg1 * vt[dd].y
                                + pg2 * vt[dd].z + pg3 * vt[dd].w;
            }
        }
    }

    // ---- reductions: sum over 16 tc lanes; out over jq bits only
#pragma unroll
    for (int m = 1; m <= 8; m <<= 1)
#pragma unroll
        for (int i = 0; i < 4; ++i) sum[i] += __shfl_xor(sum[i], m, 64);
#pragma unroll
    for (int m = 4; m <= 8; m <<= 1)
#pragma unroll
        for (int i = 0; i < 4; ++i)
#pragma unroll
            for (int dd = 0; dd < 4; ++dd) out[i][dd] += __shfl_xor(out[i][dd], m, 64);

    if (jq == 0) {
#pragma unroll
        for (int i = 0; i < 4; ++i) {
            const int rg = rt * 64 + r0 + i;
            if (rg < 500) {
                const float inv = 1.f / sum[i];
                float4 o;
                o.x = out[i][0] * inv; o.y = out[i][1] * inv;
                o.z = out[i][2] * inv; o.w = out[i][3] * inv;
                st4(&att[((size_t)(b * N_ + rg)) * 128 + h * 16 + dg * 4], o);
            }
        }
    }
}

// Pointer logits: s = mh*enc^T/sqrt(128); p = exp(10*tanh(s)+mask) stored
// unnormalized to d_out; per-row sums to rsum.
__global__ __launch_bounds__(256) void pointer_kernel(
    const float* __restrict__ mh, const float* __restrict__ enc,
    const float* __restrict__ mask, float* __restrict__ outp, float* __restrict__ rsum)
{
    __shared__ __align__(16) float Mt[16][68];
    __shared__ __align__(16) float Et[16][68];
    const int t = threadIdx.x;
    const int rt = blockIdx.x;
    const int b  = blockIdx.y;
    const int tj = t & 15;
    const int r0 = (t >> 4) * 4;
    const int g0 = tj * 4;
    const int srow = t >> 2;
    const int sde  = (t & 3) * 4;

    int rgl = rt * 64 + srow; if (rgl > 499) rgl = 499;
    float rs[4] = {0.f, 0.f, 0.f, 0.f};

    for (int gc = 0; gc < 8; ++gc) {
        float s[4][4];
#pragma unroll
        for (int i = 0; i < 4; ++i)
#pragma unroll
            for (int j = 0; j < 4; ++j) s[i][j] = 0.f;

        for (int ec = 0; ec < 8; ++ec) {
            __syncthreads();
            const float4 mv4 = ld4(&mh[((size_t)(b * N_ + rgl)) * 128 + ec * 16 + sde]);
            Mt[sde + 0][srow] = mv4.x; Mt[sde + 1][srow] = mv4.y;
            Mt[sde + 2][srow] = mv4.z; Mt[sde + 3][srow] = mv4.w;
            int gg = gc * 64 + srow; if (gg > 499) gg = 499;
            const float4 ev = ld4(&enc[((size_t)(b * N_ + gg)) * 128 + ec * 16 + sde]);
            Et[sde + 0][srow] = ev.x; Et[sde + 1][srow] = ev.y;
            Et[sde + 2][srow] = ev.z; Et[sde + 3][srow] = ev.w;
            __syncthreads();
#pragma unroll
            for (int d = 0; d < 16; ++d) {
                const float4 a4 = ld4(&Mt[d][r0]);
                const float4 e4 = ld4(&Et[d][g0]);
                const float a[4] = {a4.x, a4.y, a4.z, a4.w};
                const float e[4] = {e4.x, e4.y, e4.z, e4.w};
#pragma unroll
                for (int i = 0; i < 4; ++i)
#pragma unroll
                    for (int j = 0; j < 4; ++j) s[i][j] += a[i] * e[j];
            }
        }

#pragma unroll
        for (int i = 0; i < 4; ++i) {
            const int rg = rt * 64 + r0 + i;
            const int gg = gc * 64 + g0;
            const bool ok = (rg < 500) && (gg < 500);
            float4 mv;
            if (ok) mv = ld4(&mask[((size_t)b * N_ + rg) * N_ + gg]);
            else mv = make_float4(-1e9f, -1e9f, -1e9f, -1e9f);
            const float c = 0.08838834764831845f;  // 1/sqrt(128)
            float4 pv;
            pv.x = __expf(10.f * fast_tanh(s[i][0] * c) + mv.x);
            pv.y = __expf(10.f * fast_tanh(s[i][1] * c) + mv.y);
            pv.z = __expf(10.f * fast_tanh(s[i][2] * c) + mv.z);
            pv.w = __expf(10.f * fast_tanh(s[i][3] * c) + mv.w);
            rs[i] += pv.x + pv.y + pv.z + pv.w;
            if (ok) st4(&outp[((size_t)b * N_ + rg) * N_ + gg], pv);
        }
    }

#pragma unroll
    for (int m = 1; m < 16; m <<= 1)
#pragma unroll
        for (int i = 0; i < 4; ++i) rs[i] += __shfl_xor(rs[i], m, 64);
    if (tj == 0) {
#pragma unroll
        for (int i = 0; i < 4; ++i) {
            const int rg = rt * 64 + r0 + i;
            if (rg < 500) rsum[b * 512 + rg] = rs[i];
        }
    }
}

__global__ __launch_bounds__(128) void norm_kernel(
    float* __restrict__ outp, const float* __restrict__ rsum)
{
    const int row = blockIdx.x;
    const int t = threadIdx.x;
    if (t < 125) {
        const int b = row / 500;
        const int n = row - b * 500;
        const float inv = 1.f / rsum[b * 512 + n];
        const size_t off = (size_t)row * 500 + t * 4;
        float4 v = ld4(&outp[off]);
        v.x *= inv; v.y *= inv; v.z *= inv; v.w *= inv;
        st4(&outp[off], v);
    }
}

extern "C" void kernel_launch(void* const* d_in, const int* in_sizes, int n_in,
                              void* d_out, int out_size, void* d_ws, size_t ws_size,
                              hipStream_t stream) {
    const float* enc  = (const float*)d_in[0];
    const float* encf = (const float*)d_in[1];
    const float* encl = (const float*)d_in[2];
    const float* mask = (const float*)d_in[3];
    const float* Wqf  = (const float*)d_in[4];
    const float* Wql  = (const float*)d_in[5];
    const float* Wk   = (const float*)d_in[6];
    const float* Wv   = (const float*)d_in[7];
    const float* Wc   = (const float*)d_in[8];
    const float* bc   = (const float*)d_in[9];
    float* out = (float*)d_out;
    float* ws = (float*)d_ws;

    float* ws_q    = ws;
    float* ws_kv   = ws + 4096000;
    float* ws_att  = ws + 12288000;
    float* ws_mh   = ws_q;
    float* ws_rsum = ws_kv;

    gemm_xw<<<dim3(2, 500), 256, 0, stream>>>(encf, Wqf, nullptr, encl, Wql, nullptr,
                                              nullptr, ws_q, 128, 2);
    gemm_xw<<<dim3(4, 500), 256, 0, stream>>>(enc, Wk, Wv, nullptr, nullptr, nullptr,
                                              nullptr, ws_kv, 256, 1);
    attn_kernel<<<dim3(8, 8, 64), 256, 0, stream>>>(ws_q, ws_kv, mask, ws_att);
    gemm_xw<<<dim3(2, 500), 256, 0, stream>>>(ws_att, Wc, nullptr, nullptr, nullptr, nullptr,
                                              bc, ws_mh, 128, 1);
    pointer_kernel<<<dim3(8, 64), 256, 0, stream>>>(ws_mh, enc, mask, out, ws_rsum);
    norm_kernel<<<32000, 128, 0, stream>>>(out, ws_rsum);
}

// Round 3
// 587.968 us; speedup vs baseline: 2.6874x; 2.6874x over previous
//
#include <hip/hip_runtime.h>

// POMO decoder: B=64, N=500, E=128, H=8, D=16. All fp32.
// Pipeline:
//   K1 gemm_xw : q  = encF*WqF^T + encL*WqL^T            -> ws_q  [32000,128]
//   K2 gemm_xw : kv = encN*[Wk;Wv]^T                     -> ws_kv [32000,256]
//   K3 attn    : att[b,n,h*16+d] = softmax(qk/4+mask)*v  -> ws_att[32000,128]
//   K4 gemm_xw : mh = att*Wc^T + bc                      -> ws_mh (reuses ws_q)
//   K5 pointer : p = exp(10*tanh(mh*enc^T/sqrt128)+mask) -> d_out (unnormalized), rowsums -> ws_rsum
//   K6 norm    : d_out /= rowsum
// Softmax max-subtraction skipped: attention logits ~N(0,1.4), pointer logits
// clipped to [-10,10]; exp(-1e9) underflows to exactly 0 (matches masking).
// R3 NOTE: attn uses __launch_bounds__(256) single-arg. (256,4) in R2 forced
// the allocator under natural demand -> spill-everything (VGPR 64, 5 GB
// scratch traffic, 3.1x slowdown). Do not re-add an occupancy floor here.

#define B_ 64
#define N_ 500

__device__ __forceinline__ float4 ld4(const float* p) { return *reinterpret_cast<const float4*>(p); }
__device__ __forceinline__ void st4(float* p, const float4 v) { *reinterpret_cast<float4*>(p) = v; }

__device__ __forceinline__ float fast_tanh(float x) {
    const float e = __expf(2.f * x);
    return 1.f - 2.f / (e + 1.f);
}

// C[M,F] = sum_t A_t * W_t^T (+bias). M=32000, K=128 fixed. F in {128,256}.
__global__ __launch_bounds__(256) void gemm_xw(
    const float* __restrict__ A1, const float* __restrict__ W1a, const float* __restrict__ W1b,
    const float* __restrict__ A2, const float* __restrict__ W2a, const float* __restrict__ W2b,
    const float* __restrict__ bias, float* __restrict__ C, const int F, const int nterm)
{
    __shared__ __align__(16) float At[16][68];
    __shared__ __align__(16) float Wt[16][68];
    const int t = threadIdx.x;
    const int rb = blockIdx.y * 64;
    const int fb = blockIdx.x * 64;
    const int r0 = (t >> 4) * 4;
    const int f0 = (t & 15) * 4;
    const int srow = t >> 2;
    const int sde  = (t & 3) * 4;

    float acc[4][4];
#pragma unroll
    for (int i = 0; i < 4; ++i)
#pragma unroll
        for (int j = 0; j < 4; ++j) acc[i][j] = 0.f;

    for (int tt = 0; tt < nterm; ++tt) {
        const float* A  = tt ? A2 : A1;
        const float* Wa = tt ? W2a : W1a;
        const float* Wb = tt ? W2b : W1b;
        const float* W  = (fb < 128) ? Wa : Wb;
        const int fr = (fb & 127) + srow;
        for (int e0 = 0; e0 < 128; e0 += 16) {
            __syncthreads();
            const float4 av = ld4(&A[(size_t)(rb + srow) * 128 + e0 + sde]);
            At[sde + 0][srow] = av.x; At[sde + 1][srow] = av.y;
            At[sde + 2][srow] = av.z; At[sde + 3][srow] = av.w;
            const float4 wv = ld4(&W[(size_t)fr * 128 + e0 + sde]);
            Wt[sde + 0][srow] = wv.x; Wt[sde + 1][srow] = wv.y;
            Wt[sde + 2][srow] = wv.z; Wt[sde + 3][srow] = wv.w;
            __syncthreads();
#pragma unroll
            for (int d = 0; d < 16; ++d) {
                const float4 a4 = ld4(&At[d][r0]);
                const float4 w4 = ld4(&Wt[d][f0]);
                const float a[4] = {a4.x, a4.y, a4.z, a4.w};
                const float w[4] = {w4.x, w4.y, w4.z, w4.w};
#pragma unroll
                for (int i = 0; i < 4; ++i)
#pragma unroll
                    for (int j = 0; j < 4; ++j) acc[i][j] += a[i] * w[j];
            }
        }
    }

    float4 bv = make_float4(0.f, 0.f, 0.f, 0.f);
    if (bias) bv = ld4(&bias[fb + f0]);
#pragma unroll
    for (int i = 0; i < 4; ++i) {
        float4 o;
        o.x = acc[i][0] + bv.x; o.y = acc[i][1] + bv.y;
        o.z = acc[i][2] + bv.z; o.w = acc[i][3] + bv.w;
        st4(&C[(size_t)(rb + r0 + i) * F + fb + f0], o);
    }
}

// Attention (R2 structure, R3 register fix):
//  thread (tr, jq, dg): tr=t>>4 rows 4; jq=(t>>2)&3 j-subset; dg=t&3.
//  QK: thread scores s[4][4] at j0=16*jq+4*dg -> exp+mask -> p, row-sum partials.
//  PV: thread owns out[4 rows][4 d] (d=4*dg+dd); sibling-lane P via __shfl.
//  Vt transposed + XOR-swizzled (d,j)->Vt[d][j^(4*(d>>2))]: PV reads 2-way (free).
//  Reductions: sum over 4 lane-bits, out over jq bits only (48 shfl total).
__global__ __launch_bounds__(256) void attn_kernel(
    const float* __restrict__ q, const float* __restrict__ kv,
    const float* __restrict__ mask, float* __restrict__ att)
{
    __shared__ __align__(16) float Qt[16][68];  // [d][row]
    __shared__ __align__(16) float Kt[16][68];  // [d][j]
    __shared__ __align__(16) float Vt[16][68];  // [d][j^swz]
    const int t = threadIdx.x;
    const int lane = t & 63;
    const int rt = blockIdx.x;
    const int h  = blockIdx.y;
    const int b  = blockIdx.z;
    const int tr = t >> 4;
    const int jq = (t >> 2) & 3;
    const int dg = t & 3;
    const int r0 = tr * 4;
    const int srow = t >> 2;
    const int sde  = (t & 3) * 4;
    const int vswz = srow ^ (4 * (t & 3));

    {
        const int rg = min(rt * 64 + srow, 499);
        const float4 qa = ld4(&q[((size_t)(b * N_ + rg)) * 128 + h * 16 + sde]);
        Qt[sde + 0][srow] = qa.x; Qt[sde + 1][srow] = qa.y;
        Qt[sde + 2][srow] = qa.z; Qt[sde + 3][srow] = qa.w;
    }

    float out[4][4];
#pragma unroll
    for (int i = 0; i < 4; ++i)
#pragma unroll
        for (int dd = 0; dd < 4; ++dd) out[i][dd] = 0.f;
    float sum[4] = {0.f, 0.f, 0.f, 0.f};

    // preload chunk 0
    float4 kreg, vreg;
    {
        const int jg = min(srow, 499);
        const float* kp = &kv[((size_t)(b * N_ + jg)) * 256 + h * 16 + sde];
        kreg = ld4(kp); vreg = ld4(kp + 128);
    }

    for (int jc = 0; jc < 8; ++jc) {
        __syncthreads();
        Kt[sde + 0][srow] = kreg.x; Kt[sde + 1][srow] = kreg.y;
        Kt[sde + 2][srow] = kreg.z; Kt[sde + 3][srow] = kreg.w;
        Vt[sde + 0][vswz] = vreg.x; Vt[sde + 1][vswz] = vreg.y;
        Vt[sde + 2][vswz] = vreg.z; Vt[sde + 3][vswz] = vreg.w;
        __syncthreads();
        if (jc < 7) {
            const int jg = min(jc * 64 + 64 + srow, 499);
            const float* kp = &kv[((size_t)(b * N_ + jg)) * 256 + h * 16 + sde];
            kreg = ld4(kp); vreg = ld4(kp + 128);
        }

        // ---- QK: s[4 rows][4 j] at j0 = 16*jq + 4*dg
        const int jloc = jq * 16 + dg * 4;
        float s[4][4];
#pragma unroll
        for (int i = 0; i < 4; ++i)
#pragma unroll
            for (int j = 0; j < 4; ++j) s[i][j] = 0.f;
#pragma unroll
        for (int d = 0; d < 16; ++d) {
            const float4 a4 = ld4(&Qt[d][r0]);
            const float4 k4 = ld4(&Kt[d][jloc]);
            const float a[4] = {a4.x, a4.y, a4.z, a4.w};
            const float k[4] = {k4.x, k4.y, k4.z, k4.w};
#pragma unroll
            for (int i = 0; i < 4; ++i)
#pragma unroll
                for (int j = 0; j < 4; ++j) s[i][j] += a[i] * k[j];
        }

        // ---- exp + mask -> p, partial row sums
        const int jbase = jc * 64 + jloc;
        float p[4][4];
#pragma unroll
        for (int i = 0; i < 4; ++i) {
            const int rgc = min(rt * 64 + r0 + i, 499);
            float4 mv;
            if (jbase < 500) mv = ld4(&mask[((size_t)b * N_ + rgc) * N_ + jbase]);
            else mv = make_float4(-1e9f, -1e9f, -1e9f, -1e9f);
            p[i][0] = __expf(s[i][0] * 0.25f + mv.x);
            p[i][1] = __expf(s[i][1] * 0.25f + mv.y);
            p[i][2] = __expf(s[i][2] * 0.25f + mv.z);
            p[i][3] = __expf(s[i][3] * 0.25f + mv.w);
            sum[i] += p[i][0] + p[i][1] + p[i][2] + p[i][3];
        }

        // ---- PV: out[i][dd] over j in [16*jq, 16*jq+16)
#pragma unroll
        for (int g = 0; g < 4; ++g) {
            const int sl = (lane & ~3) | g;          // sibling lane with dg=g
            const int jb = jq * 16 + 4 * (g ^ dg);   // swizzled read base
            float4 vt[4];
#pragma unroll
            for (int dd = 0; dd < 4; ++dd) vt[dd] = ld4(&Vt[dg * 4 + dd][jb]);
#pragma unroll
            for (int i = 0; i < 4; ++i) {
                const float pg0 = __shfl(p[i][0], sl, 64);
                const float pg1 = __shfl(p[i][1], sl, 64);
                const float pg2 = __shfl(p[i][2], sl, 64);
                const float pg3 = __shfl(p[i][3], sl, 64);
#pragma unroll
                for (int dd = 0; dd < 4; ++dd)
                    out[i][dd] += pg0 * vt[dd].x + pg1 * vt[dd].y
                                + pg2 * vt[dd].z + pg3 * vt[dd].w;
            }
        }
    }

    // ---- reductions
#pragma unroll
    for (int m = 1; m <= 8; m <<= 1)
#pragma unroll
        for (int i = 0; i < 4; ++i) sum[i] += __shfl_xor(sum[i], m, 64);
#pragma unroll
    for (int m = 4; m <= 8; m <<= 1)
#pragma unroll
        for (int i = 0; i < 4; ++i)
#pragma unroll
            for (int dd = 0; dd < 4; ++dd) out[i][dd] += __shfl_xor(out[i][dd], m, 64);

    if (jq == 0) {
#pragma unroll
        for (int i = 0; i < 4; ++i) {
            const int rg = rt * 64 + r0 + i;
            if (rg < 500) {
                const float inv = 1.f / sum[i];
                float4 o;
                o.x = out[i][0] * inv; o.y = out[i][1] * inv;
                o.z = out[i][2] * inv; o.w = out[i][3] * inv;
                st4(&att[((size_t)(b * N_ + rg)) * 128 + h * 16 + dg * 4], o);
            }
        }
    }
}

// Pointer logits: s = mh*enc^T/sqrt(128); p = exp(10*tanh(s)+mask) stored
// unnormalized to d_out; per-row sums to rsum.
__global__ __launch_bounds__(256) void pointer_kernel(
    const float* __restrict__ mh, const float* __restrict__ enc,
    const float* __restrict__ mask, float* __restrict__ outp, float* __restrict__ rsum)
{
    __shared__ __align__(16) float Mt[16][68];
    __shared__ __align__(16) float Et[16][68];
    const int t = threadIdx.x;
    const int rt = blockIdx.x;
    const int b  = blockIdx.y;
    const int tj = t & 15;
    const int r0 = (t >> 4) * 4;
    const int g0 = tj * 4;
    const int srow = t >> 2;
    const int sde  = (t & 3) * 4;

    int rgl = rt * 64 + srow; if (rgl > 499) rgl = 499;
    float rs[4] = {0.f, 0.f, 0.f, 0.f};

    for (int gc = 0; gc < 8; ++gc) {
        float s[4][4];
#pragma unroll
        for (int i = 0; i < 4; ++i)
#pragma unroll
            for (int j = 0; j < 4; ++j) s[i][j] = 0.f;

        for (int ec = 0; ec < 8; ++ec) {
            __syncthreads();
            const float4 mv4 = ld4(&mh[((size_t)(b * N_ + rgl)) * 128 + ec * 16 + sde]);
            Mt[sde + 0][srow] = mv4.x; Mt[sde + 1][srow] = mv4.y;
            Mt[sde + 2][srow] = mv4.z; Mt[sde + 3][srow] = mv4.w;
            int gg = gc * 64 + srow; if (gg > 499) gg = 499;
            const float4 ev = ld4(&enc[((size_t)(b * N_ + gg)) * 128 + ec * 16 + sde]);
            Et[sde + 0][srow] = ev.x; Et[sde + 1][srow] = ev.y;
            Et[sde + 2][srow] = ev.z; Et[sde + 3][srow] = ev.w;
            __syncthreads();
#pragma unroll
            for (int d = 0; d < 16; ++d) {
                const float4 a4 = ld4(&Mt[d][r0]);
                const float4 e4 = ld4(&Et[d][g0]);
                const float a[4] = {a4.x, a4.y, a4.z, a4.w};
                const float e[4] = {e4.x, e4.y, e4.z, e4.w};
#pragma unroll
                for (int i = 0; i < 4; ++i)
#pragma unroll
                    for (int j = 0; j < 4; ++j) s[i][j] += a[i] * e[j];
            }
        }

#pragma unroll
        for (int i = 0; i < 4; ++i) {
            const int rg = rt * 64 + r0 + i;
            const int gg = gc * 64 + g0;
            const bool ok = (rg < 500) && (gg < 500);
            float4 mv;
            if (ok) mv = ld4(&mask[((size_t)b * N_ + rg) * N_ + gg]);
            else mv = make_float4(-1e9f, -1e9f, -1e9f, -1e9f);
            const float c = 0.08838834764831845f;  // 1/sqrt(128)
            float4 pv;
            pv.x = __expf(10.f * fast_tanh(s[i][0] * c) + mv.x);
            pv.y = __expf(10.f * fast_tanh(s[i][1] * c) + mv.y);
            pv.z = __expf(10.f * fast_tanh(s[i][2] * c) + mv.z);
            pv.w = __expf(10.f * fast_tanh(s[i][3] * c) + mv.w);
            rs[i] += pv.x + pv.y + pv.z + pv.w;
            if (ok) st4(&outp[((size_t)b * N_ + rg) * N_ + gg], pv);
        }
    }

#pragma unroll
    for (int m = 1; m < 16; m <<= 1)
#pragma unroll
        for (int i = 0; i < 4; ++i) rs[i] += __shfl_xor(rs[i], m, 64);
    if (tj == 0) {
#pragma unroll
        for (int i = 0; i < 4; ++i) {
            const int rg = rt * 64 + r0 + i;
            if (rg < 500) rsum[b * 512 + rg] = rs[i];
        }
    }
}

__global__ __launch_bounds__(128) void norm_kernel(
    float* __restrict__ outp, const float* __restrict__ rsum)
{
    const int row = blockIdx.x;
    const int t = threadIdx.x;
    if (t < 125) {
        const int b = row / 500;
        const int n = row - b * 500;
        const float inv = 1.f / rsum[b * 512 + n];
        const size_t off = (size_t)row * 500 + t * 4;
        float4 v = ld4(&outp[off]);
        v.x *= inv; v.y *= inv; v.z *= inv; v.w *= inv;
        st4(&outp[off], v);
    }
}

extern "C" void kernel_launch(void* const* d_in, const int* in_sizes, int n_in,
                              void* d_out, int out_size, void* d_ws, size_t ws_size,
                              hipStream_t stream) {
    const float* enc  = (const float*)d_in[0];
    const float* encf = (const float*)d_in[1];
    const float* encl = (const float*)d_in[2];
    const float* mask = (const float*)d_in[3];
    const float* Wqf  = (const float*)d_in[4];
    const float* Wql  = (const float*)d_in[5];
    const float* Wk   = (const float*)d_in[6];
    const float* Wv   = (const float*)d_in[7];
    const float* Wc   = (const float*)d_in[8];
    const float* bc   = (const float*)d_in[9];
    float* out = (float*)d_out;
    float* ws = (float*)d_ws;

    float* ws_q    = ws;
    float* ws_kv   = ws + 4096000;
    float* ws_att  = ws + 12288000;
    float* ws_mh   = ws_q;
    float* ws_rsum = ws_kv;

    gemm_xw<<<dim3(2, 500), 256, 0, stream>>>(encf, Wqf, nullptr, encl, Wql, nullptr,
                                              nullptr, ws_q, 128, 2);
    gemm_xw<<<dim3(4, 500), 256, 0, stream>>>(enc, Wk, Wv, nullptr, nullptr, nullptr,
                                              nullptr, ws_kv, 256, 1);
    attn_kernel<<<dim3(8, 8, 64), 256, 0, stream>>>(ws_q, ws_kv, mask, ws_att);
    gemm_xw<<<dim3(2, 500), 256, 0, stream>>>(ws_att, Wc, nullptr, nullptr, nullptr, nullptr,
                                              bc, ws_mh, 128, 1);
    pointer_kernel<<<dim3(8, 64), 256, 0, stream>>>(ws_mh, enc, mask, out, ws_rsum);
    norm_kernel<<<32000, 128, 0, stream>>>(out, ws_rsum);
}

// Round 4
// 538.712 us; speedup vs baseline: 2.9331x; 1.0914x over previous
//
#include <hip/hip_runtime.h>

// POMO decoder: B=64, N=500, E=128, H=8, D=16.
// Pipeline (R4):
//   K1 gemm_mfma : q  = encF*WqF^T + encL*WqL^T   (split-bf16 MFMA) -> ws_q
//   K2 gemm_mfma : kv = encN*[Wk;Wv]^T            (split-bf16 MFMA) -> ws_kv
//   K3 attn      : softmax(qk/4+mask)*v  (fp32 VALU, unchanged)     -> ws_att
//   K4 gemm_mfma : mh = att*Wc^T + bc             (split-bf16 MFMA) -> ws_mh (=ws_q)
//   K5 pointer   : p = exp(10*tanh(mh*enc^T/sqrt128)+mask) -> d_out, fused
//                  normalization epilogue (norm_kernel deleted).
// Numerics: split-bf16 (x = hi+lo, 3-term mfma) -> ~1e-5 relative error.
// Softmax max-subtraction skipped (logits bounded; exp(-1e9) flushes to 0).
// R3 NOTE: no __launch_bounds__ occupancy floors — (256,4) caused
// spill-everything (VGPR 64, 5 GB scratch). Single-arg only.

#define B_ 64
#define N_ 500

typedef short bf16x8 __attribute__((ext_vector_type(8)));
typedef float f32x16 __attribute__((ext_vector_type(16)));
typedef unsigned short ushort8 __attribute__((ext_vector_type(8)));

__device__ __forceinline__ float4 ld4(const float* p) { return *reinterpret_cast<const float4*>(p); }
__device__ __forceinline__ void st4(float* p, const float4 v) { *reinterpret_cast<float4*>(p) = v; }

__device__ __forceinline__ float fast_tanh(float x) {
    const float e = __expf(2.f * x);
    return 1.f - 2.f / (e + 1.f);
}

__device__ __forceinline__ unsigned short f2bf_rn(float x) {
    // round-to-nearest-even bf16 (inputs are finite)
    unsigned u = __float_as_uint(x);
    return (unsigned short)((u + 0x7FFFu + ((u >> 16) & 1u)) >> 16);
}
__device__ __forceinline__ float bf2f(unsigned short h) {
    return __uint_as_float(((unsigned)h) << 16);
}

// ---------------------------------------------------------------------------
// Split-bf16 MFMA GEMM: C[M,F] = sum_t A_t[M,128] * W_t[F,128]^T (+bias).
// Block: 256 thr / 4 waves; tile 64(M) x 64(F); wave = one 32x32 via
// v_mfma_f32_32x32x16_bf16, 8 k-steps, 3 mfma each (hh, hl, lh).
// LDS: 4 unpadded [64][128] bf16 planes (exactly 64 KB) with XOR chunk
// swizzle (chunk ^ (row&7)) -> quarter-wave b128 reads are 2-way (free).
// A/B fragments use the SAME k-indexing -> internal k-permutation cancels.
// ---------------------------------------------------------------------------
__global__ __launch_bounds__(256) void gemm_mfma(
    const float* __restrict__ A1, const float* __restrict__ W1a, const float* __restrict__ W1b,
    const float* __restrict__ A2, const float* __restrict__ W2a, const float* __restrict__ W2b,
    const float* __restrict__ bias, float* __restrict__ C, const int F, const int nterm)
{
    __shared__ unsigned short Ah[64 * 128];
    __shared__ unsigned short Al[64 * 128];
    __shared__ unsigned short Wh[64 * 128];
    __shared__ unsigned short Wl[64 * 128];

    const int t  = threadIdx.x;
    const int rb = blockIdx.y * 64;
    const int fb = blockIdx.x * 64;
    const int l  = t & 63;
    const int w  = t >> 6;
    const int half = l >> 5;
    const int mrow = 32 * (w >> 1) + (l & 31);
    const int ncol = 32 * (w & 1) + (l & 31);

    // staging decomposition: row = t>>2 (0..63), 32 consecutive cols
    const int sr  = t >> 2;
    const int sc0 = (t & 3) * 32;

    f32x16 acc;
#pragma unroll
    for (int i = 0; i < 16; ++i) acc[i] = 0.f;

    for (int tt = 0; tt < nterm; ++tt) {
        const float* A  = tt ? A2 : A1;
        const float* Wa = tt ? W2a : W1a;
        const float* Wb = tt ? W2b : W1b;
        const float* W  = (fb < 128) ? Wa : Wb;
        const int frbase = fb & 127;

        if (tt) __syncthreads();  // prior k-loop reads done before overwrite

        // ---- stage + split A rows [rb+sr], W rows [frbase+sr]
#pragma unroll
        for (int it = 0; it < 4; ++it) {
            const int c = sc0 + it * 8;           // elem col, 8-aligned
            const int chunk = c >> 3;
            const int dstA = sr * 128 + ((chunk ^ (sr & 7)) << 3);
            {
                const float4 v0 = ld4(&A[(size_t)(rb + sr) * 128 + c]);
                const float4 v1 = ld4(&A[(size_t)(rb + sr) * 128 + c + 4]);
                const float f[8] = {v0.x, v0.y, v0.z, v0.w, v1.x, v1.y, v1.z, v1.w};
                ushort8 hi, lo;
#pragma unroll
                for (int e = 0; e < 8; ++e) {
                    const unsigned short h = f2bf_rn(f[e]);
                    hi[e] = h;
                    lo[e] = f2bf_rn(f[e] - bf2f(h));
                }
                *reinterpret_cast<ushort8*>(&Ah[dstA]) = hi;
                *reinterpret_cast<ushort8*>(&Al[dstA]) = lo;
            }
            {
                const float4 v0 = ld4(&W[(size_t)(frbase + sr) * 128 + c]);
                const float4 v1 = ld4(&W[(size_t)(frbase + sr) * 128 + c + 4]);
                const float f[8] = {v0.x, v0.y, v0.z, v0.w, v1.x, v1.y, v1.z, v1.w};
                ushort8 hi, lo;
#pragma unroll
                for (int e = 0; e < 8; ++e) {
                    const unsigned short h = f2bf_rn(f[e]);
                    hi[e] = h;
                    lo[e] = f2bf_rn(f[e] - bf2f(h));
                }
                *reinterpret_cast<ushort8*>(&Wh[dstA]) = hi;
                *reinterpret_cast<ushort8*>(&Wl[dstA]) = lo;
            }
        }
        __syncthreads();

        // ---- 8 k-steps of 16; 3 mfma each
#pragma unroll
        for (int ks = 0; ks < 8; ++ks) {
            const int chA = (2 * ks + half) ^ (mrow & 7);
            const int chW = (2 * ks + half) ^ (ncol & 7);
            const bf16x8 ah = *reinterpret_cast<const bf16x8*>(&Ah[mrow * 128 + chA * 8]);
            const bf16x8 al = *reinterpret_cast<const bf16x8*>(&Al[mrow * 128 + chA * 8]);
            const bf16x8 wh = *reinterpret_cast<const bf16x8*>(&Wh[ncol * 128 + chW * 8]);
            const bf16x8 wl = *reinterpret_cast<const bf16x8*>(&Wl[ncol * 128 + chW * 8]);
            acc = __builtin_amdgcn_mfma_f32_32x32x16_bf16(ah, wh, acc, 0, 0, 0);
            acc = __builtin_amdgcn_mfma_f32_32x32x16_bf16(ah, wl, acc, 0, 0, 0);
            acc = __builtin_amdgcn_mfma_f32_32x32x16_bf16(al, wh, acc, 0, 0, 0);
        }
    }

    // ---- epilogue: C row = (reg&3)+8*(reg>>2)+4*half (HW-verified layout)
    const int col = fb + ncol;
    const float bv = bias ? bias[col] : 0.f;
#pragma unroll
    for (int r = 0; r < 16; ++r) {
        const int row = rb + 32 * (w >> 1) + (r & 3) + 8 * (r >> 2) + 4 * half;
        C[(size_t)row * F + col] = acc[r] + bv;
    }
}

// ---------------------------------------------------------------------------
// Attention (unchanged from R3; fp32 VALU — R5 will move this to MFMA)
// ---------------------------------------------------------------------------
__global__ __launch_bounds__(256) void attn_kernel(
    const float* __restrict__ q, const float* __restrict__ kv,
    const float* __restrict__ mask, float* __restrict__ att)
{
    __shared__ __align__(16) float Qt[16][68];
    __shared__ __align__(16) float Kt[16][68];
    __shared__ __align__(16) float Vt[16][68];
    const int t = threadIdx.x;
    const int lane = t & 63;
    const int rt = blockIdx.x;
    const int h  = blockIdx.y;
    const int b  = blockIdx.z;
    const int tr = t >> 4;
    const int jq = (t >> 2) & 3;
    const int dg = t & 3;
    const int r0 = tr * 4;
    const int srow = t >> 2;
    const int sde  = (t & 3) * 4;
    const int vswz = srow ^ (4 * (t & 3));

    {
        const int rg = min(rt * 64 + srow, 499);
        const float4 qa = ld4(&q[((size_t)(b * N_ + rg)) * 128 + h * 16 + sde]);
        Qt[sde + 0][srow] = qa.x; Qt[sde + 1][srow] = qa.y;
        Qt[sde + 2][srow] = qa.z; Qt[sde + 3][srow] = qa.w;
    }

    float out[4][4];
#pragma unroll
    for (int i = 0; i < 4; ++i)
#pragma unroll
        for (int dd = 0; dd < 4; ++dd) out[i][dd] = 0.f;
    float sum[4] = {0.f, 0.f, 0.f, 0.f};

    float4 kreg, vreg;
    {
        const int jg = min(srow, 499);
        const float* kp = &kv[((size_t)(b * N_ + jg)) * 256 + h * 16 + sde];
        kreg = ld4(kp); vreg = ld4(kp + 128);
    }

    for (int jc = 0; jc < 8; ++jc) {
        __syncthreads();
        Kt[sde + 0][srow] = kreg.x; Kt[sde + 1][srow] = kreg.y;
        Kt[sde + 2][srow] = kreg.z; Kt[sde + 3][srow] = kreg.w;
        Vt[sde + 0][vswz] = vreg.x; Vt[sde + 1][vswz] = vreg.y;
        Vt[sde + 2][vswz] = vreg.z; Vt[sde + 3][vswz] = vreg.w;
        __syncthreads();
        if (jc < 7) {
            const int jg = min(jc * 64 + 64 + srow, 499);
            const float* kp = &kv[((size_t)(b * N_ + jg)) * 256 + h * 16 + sde];
            kreg = ld4(kp); vreg = ld4(kp + 128);
        }

        const int jloc = jq * 16 + dg * 4;
        float s[4][4];
#pragma unroll
        for (int i = 0; i < 4; ++i)
#pragma unroll
            for (int j = 0; j < 4; ++j) s[i][j] = 0.f;
#pragma unroll
        for (int d = 0; d < 16; ++d) {
            const float4 a4 = ld4(&Qt[d][r0]);
            const float4 k4 = ld4(&Kt[d][jloc]);
            const float a[4] = {a4.x, a4.y, a4.z, a4.w};
            const float k[4] = {k4.x, k4.y, k4.z, k4.w};
#pragma unroll
            for (int i = 0; i < 4; ++i)
#pragma unroll
                for (int j = 0; j < 4; ++j) s[i][j] += a[i] * k[j];
        }

        const int jbase = jc * 64 + jloc;
        float p[4][4];
#pragma unroll
        for (int i = 0; i < 4; ++i) {
            const int rgc = min(rt * 64 + r0 + i, 499);
            float4 mv;
            if (jbase < 500) mv = ld4(&mask[((size_t)b * N_ + rgc) * N_ + jbase]);
            else mv = make_float4(-1e9f, -1e9f, -1e9f, -1e9f);
            p[i][0] = __expf(s[i][0] * 0.25f + mv.x);
            p[i][1] = __expf(s[i][1] * 0.25f + mv.y);
            p[i][2] = __expf(s[i][2] * 0.25f + mv.z);
            p[i][3] = __expf(s[i][3] * 0.25f + mv.w);
            sum[i] += p[i][0] + p[i][1] + p[i][2] + p[i][3];
        }

#pragma unroll
        for (int g = 0; g < 4; ++g) {
            const int sl = (lane & ~3) | g;
            const int jb = jq * 16 + 4 * (g ^ dg);
            float4 vt[4];
#pragma unroll
            for (int dd = 0; dd < 4; ++dd) vt[dd] = ld4(&Vt[dg * 4 + dd][jb]);
#pragma unroll
            for (int i = 0; i < 4; ++i) {
                const float pg0 = __shfl(p[i][0], sl, 64);
                const float pg1 = __shfl(p[i][1], sl, 64);
                const float pg2 = __shfl(p[i][2], sl, 64);
                const float pg3 = __shfl(p[i][3], sl, 64);
#pragma unroll
                for (int dd = 0; dd < 4; ++dd)
                    out[i][dd] += pg0 * vt[dd].x + pg1 * vt[dd].y
                                + pg2 * vt[dd].z + pg3 * vt[dd].w;
            }
        }
    }

#pragma unroll
    for (int m = 1; m <= 8; m <<= 1)
#pragma unroll
        for (int i = 0; i < 4; ++i) sum[i] += __shfl_xor(sum[i], m, 64);
#pragma unroll
    for (int m = 4; m <= 8; m <<= 1)
#pragma unroll
        for (int i = 0; i < 4; ++i)
#pragma unroll
            for (int dd = 0; dd < 4; ++dd) out[i][dd] += __shfl_xor(out[i][dd], m, 64);

    if (jq == 0) {
#pragma unroll
        for (int i = 0; i < 4; ++i) {
            const int rg = rt * 64 + r0 + i;
            if (rg < 500) {
                const float inv = 1.f / sum[i];
                float4 o;
                o.x = out[i][0] * inv; o.y = out[i][1] * inv;
                o.z = out[i][2] * inv; o.w = out[i][3] * inv;
                st4(&att[((size_t)(b * N_ + rg)) * 128 + h * 16 + dg * 4], o);
            }
        }
    }
}

// ---------------------------------------------------------------------------
// Pointer logits + FUSED normalization epilogue (R4): each thread rescales
// exactly the elements it wrote (no sync needed; L2-hot re-read).
// ---------------------------------------------------------------------------
__global__ __launch_bounds__(256) void pointer_kernel(
    const float* __restrict__ mh, const float* __restrict__ enc,
    const float* __restrict__ mask, float* __restrict__ outp)
{
    __shared__ __align__(16) float Mt[16][68];
    __shared__ __align__(16) float Et[16][68];
    const int t = threadIdx.x;
    const int rt = blockIdx.x;
    const int b  = blockIdx.y;
    const int tj = t & 15;
    const int r0 = (t >> 4) * 4;
    const int g0 = tj * 4;
    const int srow = t >> 2;
    const int sde  = (t & 3) * 4;

    int rgl = rt * 64 + srow; if (rgl > 499) rgl = 499;
    float rs[4] = {0.f, 0.f, 0.f, 0.f};

    for (int gc = 0; gc < 8; ++gc) {
        float s[4][4];
#pragma unroll
        for (int i = 0; i < 4; ++i)
#pragma unroll
            for (int j = 0; j < 4; ++j) s[i][j] = 0.f;

        for (int ec = 0; ec < 8; ++ec) {
            __syncthreads();
            const float4 mv4 = ld4(&mh[((size_t)(b * N_ + rgl)) * 128 + ec * 16 + sde]);
            Mt[sde + 0][srow] = mv4.x; Mt[sde + 1][srow] = mv4.y;
            Mt[sde + 2][srow] = mv4.z; Mt[sde + 3][srow] = mv4.w;
            int gg = gc * 64 + srow; if (gg > 499) gg = 499;
            const float4 ev = ld4(&enc[((size_t)(b * N_ + gg)) * 128 + ec * 16 + sde]);
            Et[sde + 0][srow] = ev.x; Et[sde + 1][srow] = ev.y;
            Et[sde + 2][srow] = ev.z; Et[sde + 3][srow] = ev.w;
            __syncthreads();
#pragma unroll
            for (int d = 0; d < 16; ++d) {
                const float4 a4 = ld4(&Mt[d][r0]);
                const float4 e4 = ld4(&Et[d][g0]);
                const float a[4] = {a4.x, a4.y, a4.z, a4.w};
                const float e[4] = {e4.x, e4.y, e4.z, e4.w};
#pragma unroll
                for (int i = 0; i < 4; ++i)
#pragma unroll
                    for (int j = 0; j < 4; ++j) s[i][j] += a[i] * e[j];
            }
        }

#pragma unroll
        for (int i = 0; i < 4; ++i) {
            const int rg = rt * 64 + r0 + i;
            const int gg = gc * 64 + g0;
            const bool ok = (rg < 500) && (gg < 500);
            float4 mv;
            if (ok) mv = ld4(&mask[((size_t)b * N_ + rg) * N_ + gg]);
            else mv = make_float4(-1e9f, -1e9f, -1e9f, -1e9f);
            const float c = 0.08838834764831845f;  // 1/sqrt(128)
            float4 pv;
            pv.x = __expf(10.f * fast_tanh(s[i][0] * c) + mv.x);
            pv.y = __expf(10.f * fast_tanh(s[i][1] * c) + mv.y);
            pv.z = __expf(10.f * fast_tanh(s[i][2] * c) + mv.z);
            pv.w = __expf(10.f * fast_tanh(s[i][3] * c) + mv.w);
            rs[i] += pv.x + pv.y + pv.z + pv.w;
            if (ok) st4(&outp[((size_t)b * N_ + rg) * N_ + gg], pv);
        }
    }

    // full row sums into every lane
#pragma unroll
    for (int m = 1; m < 16; m <<= 1)
#pragma unroll
        for (int i = 0; i < 4; ++i) rs[i] += __shfl_xor(rs[i], m, 64);

    // fused normalization: rescale own writes (no sync; same-thread RAW)
    float inv[4];
#pragma unroll
    for (int i = 0; i < 4; ++i) inv[i] = 1.f / rs[i];
    for (int gc = 0; gc < 8; ++gc) {
#pragma unroll
        for (int i = 0; i < 4; ++i) {
            const int rg = rt * 64 + r0 + i;
            const int gg = gc * 64 + g0;
            if (rg < 500 && gg < 500) {
                float* pp = &outp[((size_t)b * N_ + rg) * N_ + gg];
                float4 v = ld4(pp);
                v.x *= inv[i]; v.y *= inv[i]; v.z *= inv[i]; v.w *= inv[i];
                st4(pp, v);
            }
        }
    }
}

extern "C" void kernel_launch(void* const* d_in, const int* in_sizes, int n_in,
                              void* d_out, int out_size, void* d_ws, size_t ws_size,
                              hipStream_t stream) {
    const float* enc  = (const float*)d_in[0];
    const float* encf = (const float*)d_in[1];
    const float* encl = (const float*)d_in[2];
    const float* mask = (const float*)d_in[3];
    const float* Wqf  = (const float*)d_in[4];
    const float* Wql  = (const float*)d_in[5];
    const float* Wk   = (const float*)d_in[6];
    const float* Wv   = (const float*)d_in[7];
    const float* Wc   = (const float*)d_in[8];
    const float* bc   = (const float*)d_in[9];
    float* out = (float*)d_out;
    float* ws = (float*)d_ws;

    float* ws_q    = ws;              // [32000,128]
    float* ws_kv   = ws + 4096000;    // [32000,256]
    float* ws_att  = ws + 12288000;   // [32000,128]
    float* ws_mh   = ws_q;            // q dead after attn

    // K1: q = encF*WqF^T + encL*WqL^T
    gemm_mfma<<<dim3(2, 500), 256, 0, stream>>>(encf, Wqf, nullptr, encl, Wql, nullptr,
                                                nullptr, ws_q, 128, 2);
    // K2: kv = encN*[Wk;Wv]^T
    gemm_mfma<<<dim3(4, 500), 256, 0, stream>>>(enc, Wk, Wv, nullptr, nullptr, nullptr,
                                                nullptr, ws_kv, 256, 1);
    // K3: attention
    attn_kernel<<<dim3(8, 8, 64), 256, 0, stream>>>(ws_q, ws_kv, mask, ws_att);
    // K4: mh = att*Wc^T + bc
    gemm_mfma<<<dim3(2, 500), 256, 0, stream>>>(ws_att, Wc, nullptr, nullptr, nullptr, nullptr,
                                                bc, ws_mh, 128, 1);
    // K5: pointer logits + fused normalization
    pointer_kernel<<<dim3(8, 64), 256, 0, stream>>>(ws_mh, enc, mask, out);
}

// Round 5
// 434.250 us; speedup vs baseline: 3.6387x; 1.2406x over previous
//
#include <hip/hip_runtime.h>

// POMO decoder: B=64, N=500, E=128, H=8, D=16.
// Pipeline (R5):
//   K0 mask_pack : float mask -> 1-bit-per-entry bitmask (1=masked), stored in
//                  d_out head (2MB; d_out dead until pointer_kernel rewrites it)
//   K1 gemm_mfma : q  = encF*WqF^T + encL*WqL^T   (split-bf16 MFMA) -> ws_q
//   K2 gemm_mfma : kv = encN*[Wk;Wv]^T            (split-bf16 MFMA) -> ws_kv
//   K3 attn_mfma : swapped-QK^T (S^T = mfma(K,Q)) + bit-mask exp + in-register
//                  P->bf16 split via cvt_pk + permlane32_swap + PV MFMA -> ws_att
//   K4 gemm_mfma : mh = att*Wc^T + bc             (split-bf16 MFMA) -> ws_mh (=ws_q)
//   K5 pointer   : p = exp(10*tanh(mh*enc^T/sqrt128)+mask) -> d_out + fused norm
// Numerics: split-bf16 (x=hi+lo, 3-term mfma) ~1e-5 rel err; softmax
// max-subtraction skipped (logits bounded); bit-masked p=0 is EXACT vs
// exp(-1e9)=0. R3 NOTE: no __launch_bounds__ occupancy floors (spill cascade).

#define B_ 64
#define N_ 500

typedef short bf16x8 __attribute__((ext_vector_type(8)));
typedef float f32x16 __attribute__((ext_vector_type(16)));
typedef unsigned short ushort8 __attribute__((ext_vector_type(8)));
typedef unsigned uint2v __attribute__((ext_vector_type(2)));

__device__ __forceinline__ float4 ld4(const float* p) { return *reinterpret_cast<const float4*>(p); }
__device__ __forceinline__ void st4(float* p, const float4 v) { *reinterpret_cast<float4*>(p) = v; }

__device__ __forceinline__ float fast_tanh(float x) {
    const float e = __expf(2.f * x);
    return 1.f - 2.f / (e + 1.f);
}
__device__ __forceinline__ unsigned short f2bf_rn(float x) {
    unsigned u = __float_as_uint(x);
    return (unsigned short)((u + 0x7FFFu + ((u >> 16) & 1u)) >> 16);
}
__device__ __forceinline__ float bf2f(unsigned short h) {
    return __uint_as_float(((unsigned)h) << 16);
}
__device__ __forceinline__ unsigned cvt_pk_bf16(float lo, float hi) {
    unsigned r;
    asm("v_cvt_pk_bf16_f32 %0, %1, %2" : "=v"(r) : "v"(lo), "v"(hi));
    return r;  // low16 = bf16(lo), high16 = bf16(hi)
}

// ---------------------------------------------------------------------------
// K0: pack float mask (0 / -1e9) into bitmask: bit=1 means masked.
// Row layout: 8 u64 words (512 bits >= 500 j); j>=500 forced masked.
// ---------------------------------------------------------------------------
__global__ __launch_bounds__(256) void mask_pack(
    const float* __restrict__ mask, unsigned long long* __restrict__ bits)
{
    const int w = threadIdx.x >> 6, l = threadIdx.x & 63;
    const int n = blockIdx.x * 4 + w;  // 0..499
    const int b = blockIdx.y;
    const float* mrow = &mask[((size_t)b * N_ + n) * N_];
    unsigned long long* brow = &bits[((size_t)b * N_ + n) * 8];
#pragma unroll
    for (int c = 0; c < 8; ++c) {
        const int j = c * 64 + l;
        const bool pred = (j >= N_) || (mrow[min(j, N_ - 1)] < -1.f);
        const unsigned long long bal = __ballot(pred);
        if (l == 0) brow[c] = bal;
    }
}

// ---------------------------------------------------------------------------
// Split-bf16 MFMA GEMM (validated R4): C[M,F] = sum_t A_t * W_t^T (+bias).
// ---------------------------------------------------------------------------
__global__ __launch_bounds__(256) void gemm_mfma(
    const float* __restrict__ A1, const float* __restrict__ W1a, const float* __restrict__ W1b,
    const float* __restrict__ A2, const float* __restrict__ W2a, const float* __restrict__ W2b,
    const float* __restrict__ bias, float* __restrict__ C, const int F, const int nterm)
{
    __shared__ unsigned short Ah[64 * 128];
    __shared__ unsigned short Al[64 * 128];
    __shared__ unsigned short Wh[64 * 128];
    __shared__ unsigned short Wl[64 * 128];

    const int t  = threadIdx.x;
    const int rb = blockIdx.y * 64;
    const int fb = blockIdx.x * 64;
    const int l  = t & 63;
    const int w  = t >> 6;
    const int half = l >> 5;
    const int mrow = 32 * (w >> 1) + (l & 31);
    const int ncol = 32 * (w & 1) + (l & 31);
    const int sr  = t >> 2;
    const int sc0 = (t & 3) * 32;

    f32x16 acc;
#pragma unroll
    for (int i = 0; i < 16; ++i) acc[i] = 0.f;

    for (int tt = 0; tt < nterm; ++tt) {
        const float* A  = tt ? A2 : A1;
        const float* Wa = tt ? W2a : W1a;
        const float* Wb = tt ? W2b : W1b;
        const float* W  = (fb < 128) ? Wa : Wb;
        const int frbase = fb & 127;

        if (tt) __syncthreads();

#pragma unroll
        for (int it = 0; it < 4; ++it) {
            const int c = sc0 + it * 8;
            const int chunk = c >> 3;
            const int dstA = sr * 128 + ((chunk ^ (sr & 7)) << 3);
            {
                const float4 v0 = ld4(&A[(size_t)(rb + sr) * 128 + c]);
                const float4 v1 = ld4(&A[(size_t)(rb + sr) * 128 + c + 4]);
                const float f[8] = {v0.x, v0.y, v0.z, v0.w, v1.x, v1.y, v1.z, v1.w};
                ushort8 hi, lo;
#pragma unroll
                for (int e = 0; e < 8; ++e) {
                    const unsigned short h = f2bf_rn(f[e]);
                    hi[e] = h;
                    lo[e] = f2bf_rn(f[e] - bf2f(h));
                }
                *reinterpret_cast<ushort8*>(&Ah[dstA]) = hi;
                *reinterpret_cast<ushort8*>(&Al[dstA]) = lo;
            }
            {
                const float4 v0 = ld4(&W[(size_t)(frbase + sr) * 128 + c]);
                const float4 v1 = ld4(&W[(size_t)(frbase + sr) * 128 + c + 4]);
                const float f[8] = {v0.x, v0.y, v0.z, v0.w, v1.x, v1.y, v1.z, v1.w};
                ushort8 hi, lo;
#pragma unroll
                for (int e = 0; e < 8; ++e) {
                    const unsigned short h = f2bf_rn(f[e]);
                    hi[e] = h;
                    lo[e] = f2bf_rn(f[e] - bf2f(h));
                }
                *reinterpret_cast<ushort8*>(&Wh[dstA]) = hi;
                *reinterpret_cast<ushort8*>(&Wl[dstA]) = lo;
            }
        }
        __syncthreads();

#pragma unroll
        for (int ks = 0; ks < 8; ++ks) {
            const int chA = (2 * ks + half) ^ (mrow & 7);
            const int chW = (2 * ks + half) ^ (ncol & 7);
            const bf16x8 ah = *reinterpret_cast<const bf16x8*>(&Ah[mrow * 128 + chA * 8]);
            const bf16x8 al = *reinterpret_cast<const bf16x8*>(&Al[mrow * 128 + chA * 8]);
            const bf16x8 wh = *reinterpret_cast<const bf16x8*>(&Wh[ncol * 128 + chW * 8]);
            const bf16x8 wl = *reinterpret_cast<const bf16x8*>(&Wl[ncol * 128 + chW * 8]);
            acc = __builtin_amdgcn_mfma_f32_32x32x16_bf16(ah, wh, acc, 0, 0, 0);
            acc = __builtin_amdgcn_mfma_f32_32x32x16_bf16(ah, wl, acc, 0, 0, 0);
            acc = __builtin_amdgcn_mfma_f32_32x32x16_bf16(al, wh, acc, 0, 0, 0);
        }
    }

    const int col = fb + ncol;
    const float bv = bias ? bias[col] : 0.f;
#pragma unroll
    for (int r = 0; r < 16; ++r) {
        const int row = rb + 32 * (w >> 1) + (r & 3) + 8 * (r >> 2) + 4 * half;
        C[(size_t)row * F + col] = acc[r] + bv;
    }
}

// ---------------------------------------------------------------------------
// K3: MFMA attention. Block = 4 waves x 32 q-rows = 128 rows; grid (4,8,64).
// Per j-step (32 j): stage K (split, chunk-XOR) + V (split, transposed [d][j],
// stride 40) in LDS; S^T tile = 3x mfma(K,Q); p = bit ? 0 : exp(s); split p
// to bf16 hi/lo via cvt_pk; permlane32_swap builds PA frags; PV = 6x mfma.
// Lane&31 = q-row throughout -> row softmax is lane-local + one xor-32 add.
// ---------------------------------------------------------------------------
__global__ __launch_bounds__(256) void attn_mfma(
    const float* __restrict__ q, const float* __restrict__ kv,
    const unsigned* __restrict__ bits, float* __restrict__ att)
{
    __shared__ __align__(16) unsigned short Kh[32 * 16];
    __shared__ __align__(16) unsigned short Kl[32 * 16];
    __shared__ __align__(16) unsigned short Vh[32 * 40];  // [d][j], rows 16-31 unused
    __shared__ __align__(16) unsigned short Vl[32 * 40];
    __shared__ float Rinv[4][32];

    const int t  = threadIdx.x;
    const int w  = t >> 6;
    const int l  = t & 63;
    const int lr = l & 31;   // q-row (QK/PV-A) and d-col (PV-B)
    const int h  = l >> 5;
    const int rt = blockIdx.x;
    const int hh = blockIdx.y;
    const int b  = blockIdx.z;

    const int r_base = rt * 128 + w * 32;
    const int rc = min(r_base + lr, N_ - 1);

    // Q fragment (prescaled by 1/sqrt(D)=0.25), split hi/lo
    bf16x8 qh, ql;
    {
        const float* qp = &q[((size_t)(b * N_ + rc)) * 128 + hh * 16 + 8 * h];
        const float4 a = ld4(qp), c = ld4(qp + 4);
        const float f[8] = {a.x, a.y, a.z, a.w, c.x, c.y, c.z, c.w};
#pragma unroll
        for (int e = 0; e < 8; ++e) {
            const float v = f[e] * 0.25f;
            const unsigned short hi = f2bf_rn(v);
            qh[e] = (short)hi;
            ql[e] = (short)f2bf_rn(v - bf2f(hi));
        }
    }

    // staging assignments
    const int sj   = t >> 3;           // 0..31 (K row)
    const int sd   = (t & 7) * 2;      // 0,2,..,14 (K d-pair)
    const int kswz = sd ^ (8 * ((sj >> 2) & 1));
    const int vd   = t & 15;           // V d
    const int vj2  = (t >> 4) * 2;     // V j-pair 0..30

    const f32x16 z = {0.f};
    f32x16 out;
#pragma unroll
    for (int i = 0; i < 16; ++i) out[i] = 0.f;
    float rowsum = 0.f;

    const unsigned* brow = &bits[(size_t)(b * N_ + rc) * 16];
    const int kchunk = h ^ ((lr >> 2) & 1);

    for (int js = 0; js < 16; ++js) {
        const int j0 = js * 32;
        __syncthreads();  // previous step's LDS reads done
        {   // stage K (split + chunk-XOR swizzle)
            const int jg = min(j0 + sj, N_ - 1);
            const float2 kk = *reinterpret_cast<const float2*>(
                &kv[((size_t)(b * N_ + jg)) * 256 + hh * 16 + sd]);
            const unsigned short h0 = f2bf_rn(kk.x), h1 = f2bf_rn(kk.y);
            const unsigned short l0 = f2bf_rn(kk.x - bf2f(h0)), l1 = f2bf_rn(kk.y - bf2f(h1));
            *reinterpret_cast<unsigned*>(&Kh[sj * 16 + kswz]) = (unsigned)h0 | ((unsigned)h1 << 16);
            *reinterpret_cast<unsigned*>(&Kl[sj * 16 + kswz]) = (unsigned)l0 | ((unsigned)l1 << 16);
        }
        {   // stage V transposed [d][j]
            const int jg0 = min(j0 + vj2, N_ - 1), jg1 = min(j0 + vj2 + 1, N_ - 1);
            const float v0 = kv[((size_t)(b * N_ + jg0)) * 256 + 128 + hh * 16 + vd];
            const float v1 = kv[((size_t)(b * N_ + jg1)) * 256 + 128 + hh * 16 + vd];
            const unsigned short h0 = f2bf_rn(v0), h1 = f2bf_rn(v1);
            const unsigned short l0 = f2bf_rn(v0 - bf2f(h0)), l1 = f2bf_rn(v1 - bf2f(h1));
            *reinterpret_cast<unsigned*>(&Vh[vd * 40 + vj2]) = (unsigned)h0 | ((unsigned)h1 << 16);
            *reinterpret_cast<unsigned*>(&Vl[vd * 40 + vj2]) = (unsigned)l0 | ((unsigned)l1 << 16);
        }
        __syncthreads();

        // ---- QK^T (swapped): S^T[j][r], j reg-mapped, r = lane&31
        const bf16x8 kfh = *reinterpret_cast<const bf16x8*>(&Kh[lr * 16 + kchunk * 8]);
        const bf16x8 kfl = *reinterpret_cast<const bf16x8*>(&Kl[lr * 16 + kchunk * 8]);
        f32x16 st = __builtin_amdgcn_mfma_f32_32x32x16_bf16(kfh, qh, z, 0, 0, 0);
        st = __builtin_amdgcn_mfma_f32_32x32x16_bf16(kfh, ql, st, 0, 0, 0);
        st = __builtin_amdgcn_mfma_f32_32x32x16_bf16(kfl, qh, st, 0, 0, 0);

        // ---- masked exp (bit=1 -> 0; exact) + row-sum partials
        const unsigned bw = brow[js];
        float p[16];
#pragma unroll
        for (int g = 0; g < 16; ++g) {
            const int crow = (g & 3) + 8 * (g >> 2) + 4 * h;  // j within tile
            const float e = __expf(st[g]);
            p[g] = ((bw >> crow) & 1u) ? 0.f : e;
            rowsum += p[g];
        }

        // ---- split p to bf16 hi/lo, pack pairs
        unsigned wH[8], wL[8];
#pragma unroll
        for (int i = 0; i < 8; ++i) {
            wH[i] = cvt_pk_bf16(p[2 * i], p[2 * i + 1]);
            const float r0 = p[2 * i]     - __uint_as_float(wH[i] << 16);
            const float r1 = p[2 * i + 1] - __uint_as_float(wH[i] & 0xffff0000u);
            wL[i] = cvt_pk_bf16(r0, r1);
        }

        // ---- permlane32_swap -> PA fragments (j = 16ks + 8h + e per lane)
        const uint2v aH0 = __builtin_amdgcn_permlane32_swap(wH[0], wH[2], false, false);
        const uint2v bH0 = __builtin_amdgcn_permlane32_swap(wH[1], wH[3], false, false);
        const uint2v aH1 = __builtin_amdgcn_permlane32_swap(wH[4], wH[6], false, false);
        const uint2v bH1 = __builtin_amdgcn_permlane32_swap(wH[5], wH[7], false, false);
        const uint2v aL0 = __builtin_amdgcn_permlane32_swap(wL[0], wL[2], false, false);
        const uint2v bL0 = __builtin_amdgcn_permlane32_swap(wL[1], wL[3], false, false);
        const uint2v aL1 = __builtin_amdgcn_permlane32_swap(wL[4], wL[6], false, false);
        const uint2v bL1 = __builtin_amdgcn_permlane32_swap(wL[5], wL[7], false, false);
        union { unsigned u[4]; bf16x8 v; } pH0 = {{aH0[0], bH0[0], aH0[1], bH0[1]}};
        union { unsigned u[4]; bf16x8 v; } pH1 = {{aH1[0], bH1[0], aH1[1], bH1[1]}};
        union { unsigned u[4]; bf16x8 v; } pL0 = {{aL0[0], bL0[0], aL0[1], bL0[1]}};
        union { unsigned u[4]; bf16x8 v; } pL1 = {{aL1[0], bL1[0], aL1[1], bL1[1]}};

        // ---- PV: out[r][d] += P * V (ks = 0,1; 3-term split each)
        const bf16x8 vh0 = *reinterpret_cast<const bf16x8*>(&Vh[lr * 40 + 0 * 16 + 8 * h]);
        const bf16x8 vl0 = *reinterpret_cast<const bf16x8*>(&Vl[lr * 40 + 0 * 16 + 8 * h]);
        const bf16x8 vh1 = *reinterpret_cast<const bf16x8*>(&Vh[lr * 40 + 1 * 16 + 8 * h]);
        const bf16x8 vl1 = *reinterpret_cast<const bf16x8*>(&Vl[lr * 40 + 1 * 16 + 8 * h]);
        out = __builtin_amdgcn_mfma_f32_32x32x16_bf16(pH0.v, vh0, out, 0, 0, 0);
        out = __builtin_amdgcn_mfma_f32_32x32x16_bf16(pL0.v, vh0, out, 0, 0, 0);
        out = __builtin_amdgcn_mfma_f32_32x32x16_bf16(pH0.v, vl0, out, 0, 0, 0);
        out = __builtin_amdgcn_mfma_f32_32x32x16_bf16(pH1.v, vh1, out, 0, 0, 0);
        out = __builtin_amdgcn_mfma_f32_32x32x16_bf16(pL1.v, vh1, out, 0, 0, 0);
        out = __builtin_amdgcn_mfma_f32_32x32x16_bf16(pH1.v, vl1, out, 0, 0, 0);
    }

    // ---- epilogue: full row sums (both halves cover disjoint j), invert, store
    rowsum += __shfl_xor(rowsum, 32, 64);
    if (h == 0) Rinv[w][lr] = 1.f / rowsum;
    const float4 i0 = *reinterpret_cast<const float4*>(&Rinv[w][4 * h]);
    const float4 i1 = *reinterpret_cast<const float4*>(&Rinv[w][8 + 4 * h]);
    const float4 i2 = *reinterpret_cast<const float4*>(&Rinv[w][16 + 4 * h]);
    const float4 i3 = *reinterpret_cast<const float4*>(&Rinv[w][24 + 4 * h]);
    const float iv[16] = {i0.x, i0.y, i0.z, i0.w, i1.x, i1.y, i1.z, i1.w,
                          i2.x, i2.y, i2.z, i2.w, i3.x, i3.y, i3.z, i3.w};
    if (lr < 16) {
#pragma unroll
        for (int g = 0; g < 16; ++g) {
            const int row = r_base + (g & 3) + 8 * (g >> 2) + 4 * h;
            if (row < N_)
                att[((size_t)(b * N_ + row)) * 128 + hh * 16 + lr] = out[g] * iv[g];
        }
    }
}

// ---------------------------------------------------------------------------
// K5: pointer logits + fused normalization (unchanged from R4)
// ---------------------------------------------------------------------------
__global__ __launch_bounds__(256) void pointer_kernel(
    const float* __restrict__ mh, const float* __restrict__ enc,
    const float* __restrict__ mask, float* __restrict__ outp)
{
    __shared__ __align__(16) float Mt[16][68];
    __shared__ __align__(16) float Et[16][68];
    const int t = threadIdx.x;
    const int rt = blockIdx.x;
    const int b  = blockIdx.y;
    const int tj = t & 15;
    const int r0 = (t >> 4) * 4;
    const int g0 = tj * 4;
    const int srow = t >> 2;
    const int sde  = (t & 3) * 4;

    int rgl = rt * 64 + srow; if (rgl > 499) rgl = 499;
    float rs[4] = {0.f, 0.f, 0.f, 0.f};

    for (int gc = 0; gc < 8; ++gc) {
        float s[4][4];
#pragma unroll
        for (int i = 0; i < 4; ++i)
#pragma unroll
            for (int j = 0; j < 4; ++j) s[i][j] = 0.f;

        for (int ec = 0; ec < 8; ++ec) {
            __syncthreads();
            const float4 mv4 = ld4(&mh[((size_t)(b * N_ + rgl)) * 128 + ec * 16 + sde]);
            Mt[sde + 0][srow] = mv4.x; Mt[sde + 1][srow] = mv4.y;
            Mt[sde + 2][srow] = mv4.z; Mt[sde + 3][srow] = mv4.w;
            int gg = gc * 64 + srow; if (gg > 499) gg = 499;
            const float4 ev = ld4(&enc[((size_t)(b * N_ + gg)) * 128 + ec * 16 + sde]);
            Et[sde + 0][srow] = ev.x; Et[sde + 1][srow] = ev.y;
            Et[sde + 2][srow] = ev.z; Et[sde + 3][srow] = ev.w;
            __syncthreads();
#pragma unroll
            for (int d = 0; d < 16; ++d) {
                const float4 a4 = ld4(&Mt[d][r0]);
                const float4 e4 = ld4(&Et[d][g0]);
                const float a[4] = {a4.x, a4.y, a4.z, a4.w};
                const float e[4] = {e4.x, e4.y, e4.z, e4.w};
#pragma unroll
                for (int i = 0; i < 4; ++i)
#pragma unroll
                    for (int j = 0; j < 4; ++j) s[i][j] += a[i] * e[j];
            }
        }

#pragma unroll
        for (int i = 0; i < 4; ++i) {
            const int rg = rt * 64 + r0 + i;
            const int gg = gc * 64 + g0;
            const bool ok = (rg < 500) && (gg < 500);
            float4 mv;
            if (ok) mv = ld4(&mask[((size_t)b * N_ + rg) * N_ + gg]);
            else mv = make_float4(-1e9f, -1e9f, -1e9f, -1e9f);
            const float c = 0.08838834764831845f;  // 1/sqrt(128)
            float4 pv;
            pv.x = __expf(10.f * fast_tanh(s[i][0] * c) + mv.x);
            pv.y = __expf(10.f * fast_tanh(s[i][1] * c) + mv.y);
            pv.z = __expf(10.f * fast_tanh(s[i][2] * c) + mv.z);
            pv.w = __expf(10.f * fast_tanh(s[i][3] * c) + mv.w);
            rs[i] += pv.x + pv.y + pv.z + pv.w;
            if (ok) st4(&outp[((size_t)b * N_ + rg) * N_ + gg], pv);
        }
    }

#pragma unroll
    for (int m = 1; m < 16; m <<= 1)
#pragma unroll
        for (int i = 0; i < 4; ++i) rs[i] += __shfl_xor(rs[i], m, 64);

    float inv[4];
#pragma unroll
    for (int i = 0; i < 4; ++i) inv[i] = 1.f / rs[i];
    for (int gc = 0; gc < 8; ++gc) {
#pragma unroll
        for (int i = 0; i < 4; ++i) {
            const int rg = rt * 64 + r0 + i;
            const int gg = gc * 64 + g0;
            if (rg < 500 && gg < 500) {
                float* pp = &outp[((size_t)b * N_ + rg) * N_ + gg];
                float4 v = ld4(pp);
                v.x *= inv[i]; v.y *= inv[i]; v.z *= inv[i]; v.w *= inv[i];
                st4(pp, v);
            }
        }
    }
}

extern "C" void kernel_launch(void* const* d_in, const int* in_sizes, int n_in,
                              void* d_out, int out_size, void* d_ws, size_t ws_size,
                              hipStream_t stream) {
    const float* enc  = (const float*)d_in[0];
    const float* encf = (const float*)d_in[1];
    const float* encl = (const float*)d_in[2];
    const float* mask = (const float*)d_in[3];
    const float* Wqf  = (const float*)d_in[4];
    const float* Wql  = (const float*)d_in[5];
    const float* Wk   = (const float*)d_in[6];
    const float* Wv   = (const float*)d_in[7];
    const float* Wc   = (const float*)d_in[8];
    const float* bc   = (const float*)d_in[9];
    float* out = (float*)d_out;
    float* ws = (float*)d_ws;

    float* ws_q    = ws;              // [32000,128]
    float* ws_kv   = ws + 4096000;    // [32000,256]
    float* ws_att  = ws + 12288000;   // [32000,128]
    float* ws_mh   = ws_q;            // q dead after attn

    // bitmask scratch lives in d_out's head (2MB); d_out is rewritten by
    // pointer_kernel afterwards, so no conflict.
    unsigned long long* bits64 = (unsigned long long*)d_out;

    // K0: pack mask to bits
    mask_pack<<<dim3(125, 64), 256, 0, stream>>>(mask, bits64);
    // K1: q = encF*WqF^T + encL*WqL^T
    gemm_mfma<<<dim3(2, 500), 256, 0, stream>>>(encf, Wqf, nullptr, encl, Wql, nullptr,
                                                nullptr, ws_q, 128, 2);
    // K2: kv = encN*[Wk;Wv]^T
    gemm_mfma<<<dim3(4, 500), 256, 0, stream>>>(enc, Wk, Wv, nullptr, nullptr, nullptr,
                                                nullptr, ws_kv, 256, 1);
    // K3: MFMA attention
    attn_mfma<<<dim3(4, 8, 64), 256, 0, stream>>>(ws_q, ws_kv, (const unsigned*)d_out, ws_att);
    // K4: mh = att*Wc^T + bc
    gemm_mfma<<<dim3(2, 500), 256, 0, stream>>>(ws_att, Wc, nullptr, nullptr, nullptr, nullptr,
                                                bc, ws_mh, 128, 1);
    // K5: pointer logits + fused normalization
    pointer_kernel<<<dim3(8, 64), 256, 0, stream>>>(ws_mh, enc, mask, out);
}